// Round 1
// 1099.087 us; speedup vs baseline: 1.1369x; 1.1369x over previous
//
#include <hip/hip_runtime.h>
#include <hip/hip_bf16.h>

// Problem constants
#define NT    1024   // tokens
#define HDIM  2048
#define NEXP  64
#define IDIM  512
#define ISDIM 1024
#define KTOP  8
#define ECAP  256

typedef float  f32x4 __attribute__((ext_vector_type(4)));
typedef __bf16 bf16x8 __attribute__((ext_vector_type(8)));
typedef unsigned short u16x8 __attribute__((ext_vector_type(8)));

// k-group position within a 32-short row: phase-conflict-free XOR swizzle.
// q = k-group (0..3), r = row/column index. Including (r>>2) spreads lanes
// l15, l15+4, l15+8, l15+12 onto distinct bank groups (old swizzle left them
// colliding 4-way on reads, 16-way on the scalar B writes).
#define SWZ(r, q) ((((q) ^ ((r) & 3) ^ (((r) >> 2) & 3)) & 3) << 3)

static __device__ __forceinline__ unsigned short f2b(float f) {
  __hip_bfloat16 h = __float2bfloat16(f);
  return __builtin_bit_cast(unsigned short, h);
}
static __device__ __forceinline__ float b2f(unsigned short u) {
  return __bfloat162float(__builtin_bit_cast(__hip_bfloat16, u));
}
// lgkm-only barrier (CK block_sync_lds): keeps prefetch global loads in flight
static __device__ __forceinline__ void sync_lds() {
  __builtin_amdgcn_s_waitcnt(0xc07f);   // lgkmcnt(0), vmcnt(63), expcnt(7)
  __builtin_amdgcn_s_barrier();
}

// ---------------------------------------------------------------------------
// Router: logits fp32, top-8, renormalized softmax, expert lists, sigmoid gate
// ---------------------------------------------------------------------------
__global__ __launch_bounds__(256) void k_router(
    const float* __restrict__ x, const float* __restrict__ gw,
    const float* __restrict__ wsg,
    int* __restrict__ counts, int* __restrict__ tok_list,
    int* __restrict__ slot_map, float* __restrict__ wgt_map,
    float* __restrict__ gate_sig)
{
  __shared__ float xs[HDIM];
  __shared__ float lg[NEXP];
  __shared__ float selv[KTOP];
  __shared__ int   sele[KTOP];
  const int t = blockIdx.x, tid = threadIdx.x;
  const float* xr = x + (size_t)t * HDIM;
  for (int i = tid; i < HDIM / 4; i += 256)
    ((f32x4*)xs)[i] = ((const f32x4*)xr)[i];
  __syncthreads();
  const int wave = tid >> 6, lane = tid & 63;
  // 16 experts per wave
  for (int ei = 0; ei < 16; ++ei) {
    const int e = wave * 16 + ei;
    const float* g = gw + (size_t)e * HDIM;
    float s = 0.f;
    for (int j = lane; j < HDIM; j += 64) s += xs[j] * g[j];
    for (int off = 32; off; off >>= 1) s += __shfl_xor(s, off, 64);
    if (lane == 0) lg[e] = s;
  }
  if (wave == 1) {  // gate logit in parallel
    float s = 0.f;
    for (int j = lane; j < HDIM; j += 64) s += xs[j] * wsg[j];
    for (int off = 32; off; off >>= 1) s += __shfl_xor(s, off, 64);
    if (lane == 0) gate_sig[t] = 1.f / (1.f + __expf(-s));
  }
  __syncthreads();
  if (wave == 0) {
    float v = lg[lane];   // lane == expert id (NEXP==64)
    for (int k = 0; k < KTOP; ++k) {
      float m = v;
      for (int off = 32; off; off >>= 1) m = fmaxf(m, __shfl_xor(m, off, 64));
      unsigned long long msk = __ballot(v == m);
      int src = __ffsll(msk) - 1;   // lowest index wins ties (matches lax.top_k)
      if (lane == src) v = -3.4e38f;
      if (lane == 0) { selv[k] = m; sele[k] = src; }
    }
  }
  __syncthreads();
  if (tid < KTOP) {
    const int k = tid;
    const float mx = selv[0];
    float sum = 0.f;
    for (int i = 0; i < KTOP; ++i) sum += __expf(selv[i] - mx);
    const float w = __expf(selv[k] - mx) / sum;
    const int e = sele[k];
    const int pos = atomicAdd(&counts[e], 1);
    int slot = -1;
    if (pos < ECAP) { slot = e * ECAP + pos; tok_list[slot] = t; }
    slot_map[t * KTOP + k] = slot;
    wgt_map[t * KTOP + k] = w;
  }
}

// ---------------------------------------------------------------------------
// GEMM1: h = silu(X@W1)*(X@W3) per expert (blocks 0..255: expert g, ntile 0..3)
//        hs = silu(x@ws1)*(x@ws3) (blocks 256..287: m-group, ntile 0..7).
// BM=256, BN=128, BK=32, 512 threads (8 waves, 4m x 2n), dbuf LDS, 1 barrier/iter.
// B staged k-contiguously (coalesced dword column loads -> one b128 LDS write),
// all LDS b128 ops phase-conflict-free via SWZ.
// ---------------------------------------------------------------------------
__global__ __launch_bounds__(512, 2) void k_gemm1(
    const float* __restrict__ x,
    const float* __restrict__ w1, const float* __restrict__ w3,
    const float* __restrict__ ws1, const float* __restrict__ ws3,
    const int* __restrict__ counts, const int* __restrict__ tok_list,
    unsigned short* __restrict__ hbuf, unsigned short* __restrict__ hsbuf)
{
  __shared__ unsigned short lds[32768];   // 2 bufs x (A 8192 + B1 4096 + B3 4096)
  // XCD-chunked swizzle: consecutive logical blocks (same expert) share an XCD
  const int cpx = gridDim.x >> 3;         // 288/8 = 36
  const int b0 = blockIdx.x;
  const int bid = (b0 & 7) * cpx + (b0 >> 3);
  const int tid = threadIdx.x;
  bool is_exp;
  int g, ntile, me, ldb, m0s = 0;
  const float *b1p, *b3p;
  if (bid < NEXP * 4) {
    is_exp = true; g = bid >> 2; ntile = bid & 3;
    me = counts[g]; me = me < ECAP ? me : ECAP;
    if (me == 0) return;
    ldb = IDIM;
  } else {
    is_exp = false;
    const int s = bid - NEXP * 4;
    g = s >> 3; ntile = s & 7;
    me = 256; ldb = ISDIM; m0s = g * 256;
  }
  const int n0 = ntile * 128;
  if (is_exp) {
    b1p = w1 + (size_t)g * HDIM * IDIM + n0;
    b3p = w3 + (size_t)g * HDIM * IDIM + n0;
  } else {
    b1p = ws1 + n0;
    b3p = ws3 + n0;
  }
  // ---- A staging: thread -> row ar (0..255), k-half sel -> k [sel*16, +16) ----
  const int ar = tid & 255, sel = tid >> 8, kh = sel * 16;
  bool avalid;
  const float* arow;
  if (is_exp) {
    avalid = (ar < me);
    const int tok = avalid ? tok_list[g * ECAP + ar] : 0;
    arow = x + (size_t)tok * HDIM + kh;
  } else {
    avalid = true;
    arow = x + (size_t)(m0s + ar) * HDIM + kh;
  }
  const int aoff0 = ar * 32 + SWZ(ar, sel * 2);
  const int aoff1 = ar * 32 + SWZ(ar, sel * 2 + 1);
  // ---- B staging: thread -> column bn (0..127), k-group bg -> k [bg*8, +8) ----
  const int bn = tid & 127, bg = tid >> 7;
  const float* b1c = b1p + (size_t)(bg * 8) * ldb + bn;
  const float* b3c = b3p + (size_t)(bg * 8) * ldb + bn;
  const int boffB = bn * 32 + SWZ(bn, bg);
  // ---- fragment offsets ----
  const int lane = tid & 63, quad = lane >> 4, l15 = lane & 15;
  const int wv = tid >> 6, wm = wv >> 1, wn = wv & 1;
  const bool wactive = (wm * 64 < me);
  int aro[4], bo[4];
#pragma unroll
  for (int i = 0; i < 4; ++i) {
    const int rr = wm * 64 + i * 16 + l15;
    aro[i] = rr * 32 + SWZ(rr, quad);
    const int nn = wn * 64 + i * 16 + l15;
    bo[i] = nn * 32 + SWZ(nn, quad);
  }
  f32x4 acc1[4][4], acc3[4][4];
#pragma unroll
  for (int i = 0; i < 4; ++i)
#pragma unroll
    for (int j = 0; j < 4; ++j) {
      acc1[i][j] = f32x4{0.f, 0.f, 0.f, 0.f};
      acc3[i][j] = f32x4{0.f, 0.f, 0.f, 0.f};
    }
  f32x4 arg[4];
  float b1v[8], b3v[8];
  const int KT = HDIM / 32;   // 64
  // prologue loads (kt=0)
  if (avalid) {
    arg[0] = ((const f32x4*)arow)[0]; arg[1] = ((const f32x4*)arow)[1];
    arg[2] = ((const f32x4*)arow)[2]; arg[3] = ((const f32x4*)arow)[3];
  }
#pragma unroll
  for (int j = 0; j < 8; ++j) {
    b1v[j] = b1c[(size_t)j * ldb];
    b3v[j] = b3c[(size_t)j * ldb];
  }

  for (int kt = 0; kt < KT; ++kt) {
    unsigned short* L = lds + (kt & 1) * 16384;
    // write stage (cvt fp32->bf16), all b128 vector writes
    if (avalid) {
      u16x8 p0, p1;
#pragma unroll
      for (int i = 0; i < 4; ++i) {
        p0[i] = f2b(arg[0][i]); p0[4 + i] = f2b(arg[1][i]);
        p1[i] = f2b(arg[2][i]); p1[4 + i] = f2b(arg[3][i]);
      }
      *(u16x8*)&L[aoff0] = p0;
      *(u16x8*)&L[aoff1] = p1;
    }
    {
      u16x8 pb1, pb3;
#pragma unroll
      for (int j = 0; j < 8; ++j) { pb1[j] = f2b(b1v[j]); pb3[j] = f2b(b3v[j]); }
      *(u16x8*)&L[8192 + boffB] = pb1;
      *(u16x8*)&L[12288 + boffB] = pb3;
    }
    // prefetch next k-slice (stays in flight across the lgkm-only barrier)
    if (kt + 1 < KT) {
      const float* ap = arow + (kt + 1) * 32;
      if (avalid) {
        arg[0] = ((const f32x4*)ap)[0]; arg[1] = ((const f32x4*)ap)[1];
        arg[2] = ((const f32x4*)ap)[2]; arg[3] = ((const f32x4*)ap)[3];
      }
      const float* p1 = b1c + (size_t)(kt + 1) * 32 * ldb;
      const float* p3 = b3c + (size_t)(kt + 1) * 32 * ldb;
#pragma unroll
      for (int j = 0; j < 8; ++j) {
        b1v[j] = p1[(size_t)j * ldb];
        b3v[j] = p3[(size_t)j * ldb];
      }
    }
    sync_lds();
    if (wactive) {
      bf16x8 af[4], bf1[4], bf3[4];
#pragma unroll
      for (int i = 0; i < 4; ++i)
        af[i] = __builtin_bit_cast(bf16x8, *(const u16x8*)&L[aro[i]]);
#pragma unroll
      for (int j = 0; j < 4; ++j) {
        bf1[j] = __builtin_bit_cast(bf16x8, *(const u16x8*)&L[8192 + bo[j]]);
        bf3[j] = __builtin_bit_cast(bf16x8, *(const u16x8*)&L[12288 + bo[j]]);
      }
#pragma unroll
      for (int i = 0; i < 4; ++i)
#pragma unroll
        for (int j = 0; j < 4; ++j) {
          acc1[i][j] = __builtin_amdgcn_mfma_f32_16x16x32_bf16(af[i], bf1[j], acc1[i][j], 0, 0, 0);
          acc3[i][j] = __builtin_amdgcn_mfma_f32_16x16x32_bf16(af[i], bf3[j], acc3[i][j], 0, 0, 0);
        }
    }
  }
  // epilogue: h = silu(c1)*c3 -> bf16
  if (wactive) {
#pragma unroll
    for (int i = 0; i < 4; ++i) {
#pragma unroll
      for (int q = 0; q < 4; ++q) {
        const int rr = wm * 64 + i * 16 + quad * 4 + q;
        if (is_exp && rr >= me) continue;
        unsigned short* orow = is_exp
            ? hbuf + ((size_t)g * ECAP + rr) * IDIM
            : hsbuf + (size_t)(m0s + rr) * ISDIM;
#pragma unroll
        for (int j = 0; j < 4; ++j) {
          const int col = n0 + wn * 64 + j * 16 + l15;
          const float gg = acc1[i][j][q];
          const float uu = acc3[i][j][q];
          const float sv = (gg / (1.f + __expf(-gg))) * uu;
          orow[col] = f2b(sv);
        }
      }
    }
  }
}

// ---------------------------------------------------------------------------
// GEMM2: yb = h@W2 per expert (blocks 0..1023: expert g, ntile 0..15, bf16 out)
//        out = gate * (hs@ws2) (blocks 1024..1087: m-group, ntile 0..15, fp32).
// Same staging scheme as GEMM1.
// ---------------------------------------------------------------------------
__global__ __launch_bounds__(512, 2) void k_gemm2(
    const unsigned short* __restrict__ hbuf, const unsigned short* __restrict__ hsbuf,
    const float* __restrict__ w2, const float* __restrict__ ws2,
    const int* __restrict__ counts, const float* __restrict__ gate_sig,
    unsigned short* __restrict__ yb, float* __restrict__ out)
{
  __shared__ unsigned short lds[24576];   // 2 bufs x (A 8192 + B 4096)
  const int cpx = gridDim.x >> 3;         // 1088/8 = 136
  const int b0 = blockIdx.x;
  const int bid = (b0 & 7) * cpx + (b0 >> 3);
  const int tid = threadIdx.x;
  bool is_exp;
  int g, ntile, me, K, m0s = 0;
  const unsigned short* abase;
  const float* bbase;
  if (bid < NEXP * 16) {
    is_exp = true; g = bid >> 4; ntile = bid & 15;
    me = counts[g]; me = me < ECAP ? me : ECAP;
    if (me == 0) return;
    K = IDIM;
    abase = hbuf + (size_t)g * ECAP * IDIM;
  } else {
    is_exp = false;
    const int s = bid - NEXP * 16;
    g = s >> 4; ntile = s & 15;
    me = 256; K = ISDIM; m0s = g * 256;
    abase = hsbuf + (size_t)m0s * ISDIM;
  }
  const int n0 = ntile * 128;
  bbase = is_exp ? (w2 + (size_t)g * IDIM * HDIM + n0) : (ws2 + n0);
  // ---- A staging: row ar (0..255), k-half sel ----
  const int ar = tid & 255, sel = tid >> 8, kh = sel * 16;
  const bool avalid = (ar < me);
  const unsigned short* arow = abase + (size_t)ar * K + kh;
  const int aoff0 = ar * 32 + SWZ(ar, sel * 2);
  const int aoff1 = ar * 32 + SWZ(ar, sel * 2 + 1);
  // ---- B staging: column bn (0..127), k-group bg ----
  const int bn = tid & 127, bg = tid >> 7;
  const float* bc = bbase + (size_t)(bg * 8) * HDIM + bn;
  const int boffB = bn * 32 + SWZ(bn, bg);
  // ---- fragment offsets ----
  const int lane = tid & 63, quad = lane >> 4, l15 = lane & 15;
  const int wv = tid >> 6, wm = wv >> 1, wn = wv & 1;
  const bool wactive = (wm * 64 < me);
  int aro[4], bo[4];
#pragma unroll
  for (int i = 0; i < 4; ++i) {
    const int rr = wm * 64 + i * 16 + l15;
    aro[i] = rr * 32 + SWZ(rr, quad);
    const int nn = wn * 64 + i * 16 + l15;
    bo[i] = nn * 32 + SWZ(nn, quad);
  }
  f32x4 acc[4][4];
#pragma unroll
  for (int i = 0; i < 4; ++i)
#pragma unroll
    for (int j = 0; j < 4; ++j) acc[i][j] = f32x4{0.f, 0.f, 0.f, 0.f};
  u16x8 a0r, a1r;
  float bv[8];
  const int KT = K / 32;
  if (avalid) { a0r = ((const u16x8*)arow)[0]; a1r = ((const u16x8*)arow)[1]; }
#pragma unroll
  for (int j = 0; j < 8; ++j) bv[j] = bc[(size_t)j * HDIM];

  for (int kt = 0; kt < KT; ++kt) {
    unsigned short* L = lds + (kt & 1) * 12288;
    if (avalid) { *(u16x8*)&L[aoff0] = a0r; *(u16x8*)&L[aoff1] = a1r; }
    {
      u16x8 pb;
#pragma unroll
      for (int j = 0; j < 8; ++j) pb[j] = f2b(bv[j]);
      *(u16x8*)&L[8192 + boffB] = pb;
    }
    if (kt + 1 < KT) {
      const unsigned short* ap = arow + (kt + 1) * 32;
      if (avalid) { a0r = ((const u16x8*)ap)[0]; a1r = ((const u16x8*)ap)[1]; }
      const float* p = bc + (size_t)(kt + 1) * 32 * HDIM;
#pragma unroll
      for (int j = 0; j < 8; ++j) bv[j] = p[(size_t)j * HDIM];
    }
    sync_lds();
    if (wactive) {
      bf16x8 af[4], bfr[4];
#pragma unroll
      for (int i = 0; i < 4; ++i)
        af[i] = __builtin_bit_cast(bf16x8, *(const u16x8*)&L[aro[i]]);
#pragma unroll
      for (int j = 0; j < 4; ++j)
        bfr[j] = __builtin_bit_cast(bf16x8, *(const u16x8*)&L[8192 + bo[j]]);
#pragma unroll
      for (int i = 0; i < 4; ++i)
#pragma unroll
        for (int j = 0; j < 4; ++j)
          acc[i][j] = __builtin_amdgcn_mfma_f32_16x16x32_bf16(af[i], bfr[j], acc[i][j], 0, 0, 0);
    }
  }
  if (wactive) {
#pragma unroll
    for (int i = 0; i < 4; ++i) {
#pragma unroll
      for (int q = 0; q < 4; ++q) {
        const int rr = wm * 64 + i * 16 + quad * 4 + q;
        if (is_exp) {
          if (rr >= me) continue;
          unsigned short* orow = yb + ((size_t)g * ECAP + rr) * HDIM;
#pragma unroll
          for (int j = 0; j < 4; ++j) {
            const int col = n0 + wn * 64 + j * 16 + l15;
            orow[col] = f2b(acc[i][j][q]);
          }
        } else {
          const float gt = gate_sig[m0s + rr];
          float* orow = out + (size_t)(m0s + rr) * HDIM;
#pragma unroll
          for (int j = 0; j < 4; ++j) {
            const int col = n0 + wn * 64 + j * 16 + l15;
            orow[col] = gt * acc[i][j][q];
          }
        }
      }
    }
  }
}

// ---------------------------------------------------------------------------
// Combine: out[t] += sum_k w_k * yb[slot_k]
// ---------------------------------------------------------------------------
__global__ __launch_bounds__(256) void k_combine(
    const unsigned short* __restrict__ yb,
    const int* __restrict__ slot_map, const float* __restrict__ wgt_map,
    float* __restrict__ out)
{
  __shared__ int ss[KTOP];
  __shared__ float ww[KTOP];
  const int t = blockIdx.x, tid = threadIdx.x;
  if (tid < KTOP) { ss[tid] = slot_map[t * KTOP + tid]; ww[tid] = wgt_map[t * KTOP + tid]; }
  __syncthreads();
  const int c = tid * 8;   // 256 threads x 8 cols = 2048
  float* op = out + (size_t)t * HDIM + c;
  f32x4 o0 = ((const f32x4*)op)[0];
  f32x4 o1 = ((const f32x4*)op)[1];
  for (int k = 0; k < KTOP; ++k) {
    const int s = ss[k];
    if (s < 0) continue;
    const float w = ww[k];
    const u16x8 y = *(const u16x8*)(yb + (size_t)s * HDIM + c);
#pragma unroll
    for (int i = 0; i < 4; ++i) {
      o0[i] += w * b2f(y[i]);
      o1[i] += w * b2f(y[4 + i]);
    }
  }
  ((f32x4*)op)[0] = o0;
  ((f32x4*)op)[1] = o1;
}

// ---------------------------------------------------------------------------
extern "C" void kernel_launch(void* const* d_in, const int* in_sizes, int n_in,
                              void* d_out, int out_size, void* d_ws, size_t ws_size,
                              hipStream_t stream) {
  (void)in_sizes; (void)n_in; (void)out_size; (void)ws_size;
  const float* x   = (const float*)d_in[0];
  const float* gw  = (const float*)d_in[1];
  const float* w1  = (const float*)d_in[2];
  const float* w3  = (const float*)d_in[3];
  const float* w2  = (const float*)d_in[4];
  const float* ws1 = (const float*)d_in[5];
  const float* ws3 = (const float*)d_in[6];
  const float* ws2 = (const float*)d_in[7];
  const float* wsg = (const float*)d_in[8];
  float* out = (float*)d_out;
  char* ws = (char*)d_ws;
  // workspace layout (needs ~83 MB)
  int*   counts   = (int*)ws;                          // 256 B
  int*   tok_list = (int*)(ws + 256);                  // 64 KB
  int*   slot_map = (int*)(ws + 256 + (64 << 10));     // 32 KB
  float* wgt_map  = (float*)(ws + 256 + (96 << 10));   // 32 KB
  float* gate_sig = (float*)(ws + 256 + (128 << 10));  // 4 KB
  unsigned short* hbuf  = (unsigned short*)(ws + (1 << 20));    // 16 MB
  unsigned short* hsbuf = (unsigned short*)(ws + (17 << 20));   // 2 MB
  unsigned short* yb    = (unsigned short*)(ws + (19 << 20));   // 64 MB

  hipMemsetAsync(counts, 0, 256, stream);
  k_router<<<dim3(NT), dim3(256), 0, stream>>>(x, gw, wsg, counts, tok_list,
                                               slot_map, wgt_map, gate_sig);
  k_gemm1<<<dim3(NEXP * 4 + 32), dim3(512), 0, stream>>>(x, w1, w3, ws1, ws3,
                                                         counts, tok_list, hbuf, hsbuf);
  k_gemm2<<<dim3(NEXP * 16 + 64), dim3(512), 0, stream>>>(hbuf, hsbuf, w2, ws2,
                                                          counts, gate_sig, yb, out);
  k_combine<<<dim3(NT), dim3(256), 0, stream>>>(yb, slot_map, wgt_map, out);
}